// Round 4
// baseline (235.058 us; speedup 1.0000x reference)
//
#include <hip/hip_runtime.h>

#define B_DIM 8
#define T_DIM 2048
#define C_DIM 1024
#define H_DIM 128

typedef __attribute__((ext_vector_type(8))) short bf16x8;
typedef __attribute__((ext_vector_type(4))) float f32x4;

__device__ __forceinline__ short f2bf(float f) {
  union { float f; unsigned u; } v; v.f = f;
  unsigned u = v.u;
  unsigned r = (u + 0x7FFFu + ((u >> 16) & 1u)) >> 16;
  return (short)r;
}

// pack two fp32 -> two bf16 (round-half-up: +0x8000, truncate). 3 VALU.
__device__ __forceinline__ unsigned pk2(float a, float b) {
  union { float f; unsigned u; } ua, ub;
  ua.f = a; ub.f = b;
  return __builtin_amdgcn_perm(ub.u + 0x8000u, ua.u + 0x8000u, 0x07060302u);
}

// ---------------------------------------------------------------------------
// prep: W{k,q,v} [C][H] fp32 -> Wt[384][1024] bf16 transposed (row = h', col=c)
// ---------------------------------------------------------------------------
__global__ __launch_bounds__(256) void prep_kernel(
    const float* __restrict__ Wk, const float* __restrict__ Wq,
    const float* __restrict__ Wv, short* __restrict__ Wt) {
  int idx = blockIdx.x * 256 + threadIdx.x;   // 0 .. 393215
  int c = idx & 1023;
  int hw = idx >> 10;
  int h = hw & 127;
  int w = hw >> 7;
  const float* W = (w == 0) ? Wk : ((w == 1) ? Wq : Wv);
  Wt[((w * 128 + h) << 10) + c] = f2bf(W[(c << 7) + h]);
}

// ---------------------------------------------------------------------------
// proj: out[m][h'] = sum_c x[m][c] * Wt[h'][c].  128x128 tile, BK=32.
// A (x fp32) converted to bf16 during staging; A & B register-prefetched.
// g: 0 -> Kb, 1 -> Qb (row-major [m][128]), 2 -> Vt ([b][h][t]).
// ---------------------------------------------------------------------------
__global__ __launch_bounds__(256) void proj_kernel(
    const float* __restrict__ x, const short* __restrict__ Wt,
    short* __restrict__ Kb, short* __restrict__ Qb, short* __restrict__ Vt) {
  __shared__ __align__(16) char smem[34816];
  short* As = (short*)smem;               // [128][32]
  short* Bs = (short*)(smem + 8192);      // [128][32]
  short (*Tp)[136] = (short(*)[136])smem; // epilogue repack

  const int g  = blockIdx.y;
  const int m0 = blockIdx.x * 128;
  const int tid  = threadIdx.x;
  const int lane = tid & 63;
  const int wv   = tid >> 6;
  const int n    = lane & 15;
  const int quad = lane >> 4;
  const int mbase = (wv >> 1) * 64;
  const int nbase = (wv & 1) * 64;

  // staging: thread -> (row = tid>>1, col half = tid&1), 16 elems
  const int srow = tid >> 1;
  const int sc16 = (tid & 1) * 16;
  const float* gA = x + (size_t)(m0 + srow) * C_DIM + sc16;
  const short* gB = Wt + (size_t)(g * 128 + srow) * C_DIM + sc16;

  float4 fA[4];
  int4 rB[2];
#pragma unroll
  for (int j = 0; j < 4; j++) fA[j] = ((const float4*)gA)[j];
#pragma unroll
  for (int j = 0; j < 2; j++) rB[j] = ((const int4*)gB)[j];

  f32x4 acc[4][4];
#pragma unroll
  for (int i = 0; i < 4; i++)
#pragma unroll
    for (int j = 0; j < 4; j++) {
      f32x4 z = {0.f, 0.f, 0.f, 0.f};
      acc[i][j] = z;
    }

  for (int k0 = 0; k0 < C_DIM; k0 += 32) {
    __syncthreads();   // prev iter fragment reads done
    {
      __attribute__((aligned(16))) unsigned ua[8];
      ua[0] = pk2(fA[0].x, fA[0].y); ua[1] = pk2(fA[0].z, fA[0].w);
      ua[2] = pk2(fA[1].x, fA[1].y); ua[3] = pk2(fA[1].z, fA[1].w);
      ua[4] = pk2(fA[2].x, fA[2].y); ua[5] = pk2(fA[2].z, fA[2].w);
      ua[6] = pk2(fA[3].x, fA[3].y); ua[7] = pk2(fA[3].z, fA[3].w);
      ((int4*)(As + srow * 32 + sc16))[0] = ((int4*)ua)[0];
      ((int4*)(As + srow * 32 + sc16))[1] = ((int4*)ua)[1];
      ((int4*)(Bs + srow * 32 + sc16))[0] = rB[0];
      ((int4*)(Bs + srow * 32 + sc16))[1] = rB[1];
    }
    __syncthreads();   // staging visible
    if (k0 + 32 < C_DIM) {   // prefetch next K-slab; latency hidden by MFMA
#pragma unroll
      for (int j = 0; j < 4; j++) fA[j] = ((const float4*)(gA + k0 + 32))[j];
#pragma unroll
      for (int j = 0; j < 2; j++) rB[j] = ((const int4*)(gB + k0 + 32))[j];
    }

    bf16x8 aF[4], bF[4];
#pragma unroll
    for (int mt = 0; mt < 4; mt++)
      aF[mt] = *(const bf16x8*)(As + (mbase + mt * 16 + n) * 32 + quad * 8);
#pragma unroll
    for (int nt = 0; nt < 4; nt++)
      bF[nt] = *(const bf16x8*)(Bs + (nbase + nt * 16 + n) * 32 + quad * 8);
#pragma unroll
    for (int mt = 0; mt < 4; mt++)
#pragma unroll
      for (int nt = 0; nt < 4; nt++)
        acc[mt][nt] = __builtin_amdgcn_mfma_f32_16x16x32_bf16(
            aF[mt], bF[nt], acc[mt][nt], 0, 0, 0);
  }

  // epilogue: repack through LDS for coalesced stores
  __syncthreads();
#pragma unroll
  for (int mt = 0; mt < 4; mt++)
#pragma unroll
    for (int nt = 0; nt < 4; nt++)
#pragma unroll
      for (int i = 0; i < 4; i++) {
        int rowt = mbase + mt * 16 + quad * 4 + i;  // t-local
        int colh = nbase + nt * 16 + n;             // h-local
        short v = f2bf(acc[mt][nt][i]);
        if (g == 2) Tp[colh][rowt] = v;
        else        Tp[rowt][colh] = v;
      }
  __syncthreads();
  {
    int row = tid >> 1, half = tid & 1;
    const short* src = &Tp[row][half * 64];
    short* dst;
    if (g == 0)      dst = Kb + (size_t)(m0 + row) * H_DIM + half * 64;
    else if (g == 1) dst = Qb + (size_t)(m0 + row) * H_DIM + half * 64;
    else {
      int bb = m0 >> 11, t0 = m0 & (T_DIM - 1);
      dst = Vt + ((size_t)bb * H_DIM + row) * T_DIM + t0 + half * 64;
    }
    // 64 shorts per thread = 8 x int4  (R2/R3 bug: was j < 4 -> half the
    // tile left unwritten as 0xAA poison)
#pragma unroll
    for (int j = 0; j < 8; j++)
      *(int4*)(dst + j * 8) = *(const int4*)(src + j * 8);
  }
}

// ---------------------------------------------------------------------------
// attn pass 1: flash-decode partials over KV segments (<= 8 iters of 64).
// Segment count per qt: ceil((qt+1)/8); 80 flat per b; heavy-first.
// ---------------------------------------------------------------------------
__device__ __forceinline__ int seg_prefix(int qt) {
  return qt < 8 ? qt : qt < 16 ? 8 + ((qt - 8) << 1)
                    : qt < 24 ? 24 + (qt - 16) * 3 : 48 + ((qt - 24) << 2);
}

__global__ __launch_bounds__(256) void attn_part(
    const short* __restrict__ Qb, const short* __restrict__ Kb,
    const short* __restrict__ Vt, float* __restrict__ Opart,
    float* __restrict__ Ml) {
  const int f = 79 - blockIdx.x;   // heavy (qt=31) first
  const int b = blockIdx.y;
  int qt, seg;
  if (f < 8)       { qt = f;                  seg = 0; }
  else if (f < 24) { qt = 8 + ((f - 8) >> 1);  seg = (f - 8) & 1; }
  else if (f < 48) { qt = 16 + (f - 24) / 3;   seg = (f - 24) % 3; }
  else             { qt = 24 + ((f - 48) >> 2); seg = (f - 48) & 3; }
  const int nseg = (qt + 8) >> 3;
  const int n_it = qt + 1;
  const int bi = n_it / nseg, rem = n_it - bi * nseg;
  const int it0 = seg * bi + (seg < rem ? seg : rem);
  const int it1 = it0 + bi + (seg < rem ? 1 : 0);

  const int q0 = qt * 64;
  const int tid  = threadIdx.x;
  const int lane = tid & 63;
  const int wv   = tid >> 6;
  const int n    = lane & 15;
  const int quad = lane >> 4;

  __shared__ short Ks[64][136];
  __shared__ short Vs[128][72];
  __shared__ short Ps[4][16][72];

  bf16x8 aQ[4];
  {
    const short* qrow = Qb + (size_t)(b * T_DIM + q0 + wv * 16 + n) * H_DIM;
#pragma unroll
    for (int kc = 0; kc < 4; kc++)
      aQ[kc] = *(const bf16x8*)(qrow + kc * 32 + quad * 8);
  }

  f32x4 accO[8];
#pragma unroll
  for (int i = 0; i < 8; i++) {
    f32x4 z = {0.f, 0.f, 0.f, 0.f};
    accO[i] = z;
  }
  float mrow[4] = {-1e30f, -1e30f, -1e30f, -1e30f};
  float lrow[4] = {0.f, 0.f, 0.f, 0.f};
  const float scale = 0.08838834764831845f;  // 1/sqrt(128)
  const int row0 = q0 + wv * 16 + quad * 4;

  const short* kbase = Kb + (size_t)b * T_DIM * H_DIM;
  const short* vbase = Vt + (size_t)b * H_DIM * T_DIM;
  const int krow = tid >> 4, kcol = (tid & 15) * 8;
  const int vrow = tid >> 3, vcol = (tid & 7) * 8;

  int4 kreg[4], vreg[4];
#pragma unroll
  for (int p = 0; p < 4; p++) {
    kreg[p] = *(const int4*)(kbase + (size_t)(it0 * 64 + krow + p * 16) * H_DIM + kcol);
    vreg[p] = *(const int4*)(vbase + (size_t)(vrow + p * 32) * T_DIM + it0 * 64 + vcol);
  }

  for (int it = it0; it < it1; ++it) {
    const int j0 = it * 64;
    __syncthreads();   // prev iter's Ks/Vs reads done
#pragma unroll
    for (int p = 0; p < 4; p++) *(int4*)&Ks[krow + p * 16][kcol] = kreg[p];
#pragma unroll
    for (int p = 0; p < 4; p++) *(int4*)&Vs[vrow + p * 32][vcol] = vreg[p];
    __syncthreads();   // staging visible
    if (it + 1 < it1) {   // prefetch next tile
#pragma unroll
      for (int p = 0; p < 4; p++) {
        kreg[p] = *(const int4*)(kbase + (size_t)(j0 + 64 + krow + p * 16) * H_DIM + kcol);
        vreg[p] = *(const int4*)(vbase + (size_t)(vrow + p * 32) * T_DIM + j0 + 64 + vcol);
      }
    }

    // S = Q K^T
    f32x4 accS[4];
#pragma unroll
    for (int nt = 0; nt < 4; nt++) {
      f32x4 z = {0.f, 0.f, 0.f, 0.f};
      accS[nt] = z;
    }
#pragma unroll
    for (int nt = 0; nt < 4; nt++)
#pragma unroll
      for (int kc = 0; kc < 4; kc++) {
        bf16x8 bK = *(const bf16x8*)&Ks[nt * 16 + n][kc * 32 + quad * 8];
        accS[nt] = __builtin_amdgcn_mfma_f32_16x16x32_bf16(aQ[kc], bK, accS[nt], 0, 0, 0);
      }

    // scale + causal mask + online softmax
    float sv[4][4];
    float mt4[4] = {-1e30f, -1e30f, -1e30f, -1e30f};
#pragma unroll
    for (int nt = 0; nt < 4; nt++) {
      int col = j0 + nt * 16 + n;
#pragma unroll
      for (int i = 0; i < 4; i++) {
        float s = accS[nt][i] * scale;
        if (col > row0 + i) s = -1e30f;
        sv[nt][i] = s;
        mt4[i] = fmaxf(mt4[i], s);
      }
    }
#pragma unroll
    for (int i = 0; i < 4; i++) {
#pragma unroll
      for (int off = 1; off < 16; off <<= 1)
        mt4[i] = fmaxf(mt4[i], __shfl_xor(mt4[i], off, 64));
    }
    float alpha[4], rsum[4];
#pragma unroll
    for (int i = 0; i < 4; i++) {
      float mnew = fmaxf(mrow[i], mt4[i]);
      alpha[i] = __expf(mrow[i] - mnew);
      mrow[i] = mnew;
      rsum[i] = 0.f;
    }
#pragma unroll
    for (int nt = 0; nt < 4; nt++)
#pragma unroll
      for (int i = 0; i < 4; i++) {
        float p = __expf(sv[nt][i] - mrow[i]);
        rsum[i] += p;
        Ps[wv][quad * 4 + i][nt * 16 + n] = f2bf(p);
      }
#pragma unroll
    for (int i = 0; i < 4; i++) {
#pragma unroll
      for (int off = 1; off < 16; off <<= 1)
        rsum[i] += __shfl_xor(rsum[i], off, 64);
      lrow[i] = lrow[i] * alpha[i] + rsum[i];
    }
#pragma unroll
    for (int ht = 0; ht < 8; ht++)
#pragma unroll
      for (int i = 0; i < 4; i++)
        accO[ht][i] *= alpha[i];

    __syncthreads();   // Ps visible

    // O += P V
    bf16x8 aP[2];
#pragma unroll
    for (int kc = 0; kc < 2; kc++)
      aP[kc] = *(const bf16x8*)&Ps[wv][n][kc * 32 + quad * 8];
#pragma unroll
    for (int ht = 0; ht < 8; ht++)
#pragma unroll
      for (int kc = 0; kc < 2; kc++) {
        bf16x8 bV = *(const bf16x8*)&Vs[ht * 16 + n][kc * 32 + quad * 8];
        accO[ht] = __builtin_amdgcn_mfma_f32_16x16x32_bf16(aP[kc], bV, accO[ht], 0, 0, 0);
      }
  }

  // partials out (unnormalized O; m, l per row)
  const int pid = b * 80 + f;
  float* Ob = Opart + (size_t)pid * 8192;
#pragma unroll
  for (int ht = 0; ht < 8; ht++)
#pragma unroll
    for (int i = 0; i < 4; i++)
      Ob[(wv * 16 + quad * 4 + i) * 128 + ht * 16 + n] = accO[ht][i];
  if (n == 0) {
#pragma unroll
    for (int i = 0; i < 4; i++) {
      Ml[pid * 128 + wv * 16 + quad * 4 + i] = mrow[i];
      Ml[pid * 128 + 64 + wv * 16 + quad * 4 + i] = lrow[i];
    }
  }
}

// ---------------------------------------------------------------------------
// attn pass 2: merge <=4 partials per (b, qt), normalize, write out fp32.
// ---------------------------------------------------------------------------
__global__ __launch_bounds__(256) void attn_merge(
    const float* __restrict__ Opart, const float* __restrict__ Ml,
    float* __restrict__ out) {
  const int qt = blockIdx.x, b = blockIdx.y;
  const int nseg = (qt + 8) >> 3;
  const int tid = threadIdx.x;
  const int row = tid >> 2, cg = tid & 3;
  const int pid0 = b * 80 + seg_prefix(qt);

  float m[4], l[4], w[4];
  float M = -1e30f;
  for (int s = 0; s < nseg; s++) {
    m[s] = Ml[(pid0 + s) * 128 + row];
    l[s] = Ml[(pid0 + s) * 128 + 64 + row];
    M = fmaxf(M, m[s]);
  }
  float L = 0.f;
  for (int s = 0; s < nseg; s++) {
    w[s] = __expf(m[s] - M);
    L += l[s] * w[s];
  }
  const float inv = 1.0f / L;

  const float* src0 = Opart + (size_t)pid0 * 8192 + row * 128 + cg * 32;
  float* dst = out + (size_t)(b * T_DIM + qt * 64 + row) * H_DIM + cg * 32;
#pragma unroll
  for (int j = 0; j < 8; j++) {
    float4 a = ((const float4*)(src0))[j];
    float4 r;
    r.x = a.x * w[0]; r.y = a.y * w[0]; r.z = a.z * w[0]; r.w = a.w * w[0];
    for (int s = 1; s < nseg; s++) {
      float4 c = ((const float4*)(src0 + s * 8192))[j];
      r.x += c.x * w[s]; r.y += c.y * w[s]; r.z += c.z * w[s]; r.w += c.w * w[s];
    }
    r.x *= inv; r.y *= inv; r.z *= inv; r.w *= inv;
    ((float4*)dst)[j] = r;
  }
}

// ---------------------------------------------------------------------------
extern "C" void kernel_launch(void* const* d_in, const int* in_sizes, int n_in,
                              void* d_out, int out_size, void* d_ws, size_t ws_size,
                              hipStream_t stream) {
  (void)in_sizes; (void)n_in; (void)out_size; (void)ws_size;
  const float* x  = (const float*)d_in[0];
  const float* Wk = (const float*)d_in[1];
  const float* Wq = (const float*)d_in[2];
  const float* Wv = (const float*)d_in[3];
  float* out = (float*)d_out;

  char* ws = (char*)d_ws;
  short* Wt = (short*)ws;                         //   786,432 B
  short* Qb = (short*)(ws + 786432);              // 4,194,304 B
  short* Kb = (short*)(ws + 786432 + 4194304);    // 4,194,304 B
  short* Vt = (short*)(ws + 786432 + 8388608);    // 4,194,304 B
  float* Opart = (float*)(ws + 13369344);         // 20,971,520 B
  float* Ml    = (float*)(ws + 34340864);         //    327,680 B  (peak 33.1 MiB)

  prep_kernel<<<dim3(1536), dim3(256), 0, stream>>>(Wk, Wq, Wv, Wt);
  proj_kernel<<<dim3(128, 3), dim3(256), 0, stream>>>(x, Wt, Kb, Qb, Vt);
  attn_part<<<dim3(80, 8), dim3(256), 0, stream>>>(Qb, Kb, Vt, Opart, Ml);
  attn_merge<<<dim3(32, 8), dim3(256), 0, stream>>>(Opart, Ml, out);
}

// Round 5
// 231.778 us; speedup vs baseline: 1.0142x; 1.0142x over previous
//
#include <hip/hip_runtime.h>

#define B_DIM 8
#define T_DIM 2048
#define C_DIM 1024
#define H_DIM 128

typedef __attribute__((ext_vector_type(8))) short bf16x8;
typedef __attribute__((ext_vector_type(4))) float f32x4;

__device__ __forceinline__ short f2bf(float f) {
  union { float f; unsigned u; } v; v.f = f;
  unsigned u = v.u;
  unsigned r = (u + 0x7FFFu + ((u >> 16) & 1u)) >> 16;
  return (short)r;
}

// pack two fp32 -> two bf16 (round-half-up: +0x8000, truncate). 3 VALU.
__device__ __forceinline__ unsigned pk2(float a, float b) {
  union { float f; unsigned u; } ua, ub;
  ua.f = a; ub.f = b;
  return __builtin_amdgcn_perm(ub.u + 0x8000u, ua.u + 0x8000u, 0x07060302u);
}

// ---------------------------------------------------------------------------
// prep: W{k,q,v} [C][H] fp32 -> Wt[384][1024] bf16 transposed (row = h', col=c)
// ---------------------------------------------------------------------------
__global__ __launch_bounds__(256) void prep_kernel(
    const float* __restrict__ Wk, const float* __restrict__ Wq,
    const float* __restrict__ Wv, short* __restrict__ Wt) {
  int idx = blockIdx.x * 256 + threadIdx.x;   // 0 .. 393215
  int c = idx & 1023;
  int hw = idx >> 10;
  int h = hw & 127;
  int w = hw >> 7;
  const float* W = (w == 0) ? Wk : ((w == 1) ? Wq : Wv);
  Wt[((w * 128 + h) << 10) + c] = f2bf(W[(c << 7) + h]);
}

// ---------------------------------------------------------------------------
// proj: out[m][h'] = sum_c x[m][c] * Wt[h'][c].  128x128 tile, BK=32.
// A (x fp32) converted to bf16 during staging; A & B register-prefetched.
// g: 0 -> Kb, 1 -> Qb (row-major [m][128]), 2 -> Vt ([b][h][t]).
// ---------------------------------------------------------------------------
__global__ __launch_bounds__(256) void proj_kernel(
    const float* __restrict__ x, const short* __restrict__ Wt,
    short* __restrict__ Kb, short* __restrict__ Qb, short* __restrict__ Vt) {
  __shared__ __align__(16) char smem[34816];
  short* As = (short*)smem;               // [128][32]
  short* Bs = (short*)(smem + 8192);      // [128][32]
  short (*Tp)[136] = (short(*)[136])smem; // epilogue repack

  const int g  = blockIdx.y;
  const int m0 = blockIdx.x * 128;
  const int tid  = threadIdx.x;
  const int lane = tid & 63;
  const int wv   = tid >> 6;
  const int n    = lane & 15;
  const int quad = lane >> 4;
  const int mbase = (wv >> 1) * 64;
  const int nbase = (wv & 1) * 64;

  // staging: thread -> (row = tid>>1, col half = tid&1), 16 elems
  const int srow = tid >> 1;
  const int sc16 = (tid & 1) * 16;
  const float* gA = x + (size_t)(m0 + srow) * C_DIM + sc16;
  const short* gB = Wt + (size_t)(g * 128 + srow) * C_DIM + sc16;

  float4 fA[4];
  int4 rB[2];
#pragma unroll
  for (int j = 0; j < 4; j++) fA[j] = ((const float4*)gA)[j];
#pragma unroll
  for (int j = 0; j < 2; j++) rB[j] = ((const int4*)gB)[j];

  f32x4 acc[4][4];
#pragma unroll
  for (int i = 0; i < 4; i++)
#pragma unroll
    for (int j = 0; j < 4; j++) {
      f32x4 z = {0.f, 0.f, 0.f, 0.f};
      acc[i][j] = z;
    }

  for (int k0 = 0; k0 < C_DIM; k0 += 32) {
    __syncthreads();   // prev iter fragment reads done
    {
      __attribute__((aligned(16))) unsigned ua[8];
      ua[0] = pk2(fA[0].x, fA[0].y); ua[1] = pk2(fA[0].z, fA[0].w);
      ua[2] = pk2(fA[1].x, fA[1].y); ua[3] = pk2(fA[1].z, fA[1].w);
      ua[4] = pk2(fA[2].x, fA[2].y); ua[5] = pk2(fA[2].z, fA[2].w);
      ua[6] = pk2(fA[3].x, fA[3].y); ua[7] = pk2(fA[3].z, fA[3].w);
      ((int4*)(As + srow * 32 + sc16))[0] = ((int4*)ua)[0];
      ((int4*)(As + srow * 32 + sc16))[1] = ((int4*)ua)[1];
      ((int4*)(Bs + srow * 32 + sc16))[0] = rB[0];
      ((int4*)(Bs + srow * 32 + sc16))[1] = rB[1];
    }
    __syncthreads();   // staging visible
    if (k0 + 32 < C_DIM) {   // prefetch next K-slab; latency hidden by MFMA
#pragma unroll
      for (int j = 0; j < 4; j++) fA[j] = ((const float4*)(gA + k0 + 32))[j];
#pragma unroll
      for (int j = 0; j < 2; j++) rB[j] = ((const int4*)(gB + k0 + 32))[j];
    }

    bf16x8 aF[4], bF[4];
#pragma unroll
    for (int mt = 0; mt < 4; mt++)
      aF[mt] = *(const bf16x8*)(As + (mbase + mt * 16 + n) * 32 + quad * 8);
#pragma unroll
    for (int nt = 0; nt < 4; nt++)
      bF[nt] = *(const bf16x8*)(Bs + (nbase + nt * 16 + n) * 32 + quad * 8);
#pragma unroll
    for (int mt = 0; mt < 4; mt++)
#pragma unroll
      for (int nt = 0; nt < 4; nt++)
        acc[mt][nt] = __builtin_amdgcn_mfma_f32_16x16x32_bf16(
            aF[mt], bF[nt], acc[mt][nt], 0, 0, 0);
  }

  // epilogue: repack through LDS for coalesced stores
  __syncthreads();
#pragma unroll
  for (int mt = 0; mt < 4; mt++)
#pragma unroll
    for (int nt = 0; nt < 4; nt++)
#pragma unroll
      for (int i = 0; i < 4; i++) {
        int rowt = mbase + mt * 16 + quad * 4 + i;  // t-local
        int colh = nbase + nt * 16 + n;             // h-local
        short v = f2bf(acc[mt][nt][i]);
        if (g == 2) Tp[colh][rowt] = v;
        else        Tp[rowt][colh] = v;
      }
  __syncthreads();
  {
    int row = tid >> 1, half = tid & 1;
    const short* src = &Tp[row][half * 64];
    short* dst;
    if (g == 0)      dst = Kb + (size_t)(m0 + row) * H_DIM + half * 64;
    else if (g == 1) dst = Qb + (size_t)(m0 + row) * H_DIM + half * 64;
    else {
      int bb = m0 >> 11, t0 = m0 & (T_DIM - 1);
      dst = Vt + ((size_t)bb * H_DIM + row) * T_DIM + t0 + half * 64;
    }
#pragma unroll
    for (int j = 0; j < 8; j++)
      *(int4*)(dst + j * 8) = *(const int4*)(src + j * 8);
  }
}

// ---------------------------------------------------------------------------
// attn pass 1: flash-decode partials over KV segments (<= 8 iters of 64).
// S^T formulation: St = K·Q^T via MFMA operand swap -> softmax reduction is
// in-lane (16 vals) + 2 butterfly shuffles; alpha broadcast = 4 bpermutes.
// ---------------------------------------------------------------------------
__device__ __forceinline__ int seg_prefix(int qt) {
  return qt < 8 ? qt : qt < 16 ? 8 + ((qt - 8) << 1)
                    : qt < 24 ? 24 + (qt - 16) * 3 : 48 + ((qt - 24) << 2);
}

__global__ __launch_bounds__(256) void attn_part(
    const short* __restrict__ Qb, const short* __restrict__ Kb,
    const short* __restrict__ Vt, float* __restrict__ Opart,
    float* __restrict__ Ml) {
  const int f = 79 - blockIdx.x;   // heavy (qt=31) first
  const int b = blockIdx.y;
  int qt, seg;
  if (f < 8)       { qt = f;                  seg = 0; }
  else if (f < 24) { qt = 8 + ((f - 8) >> 1);  seg = (f - 8) & 1; }
  else if (f < 48) { qt = 16 + (f - 24) / 3;   seg = (f - 24) % 3; }
  else             { qt = 24 + ((f - 48) >> 2); seg = (f - 48) & 3; }
  const int nseg = (qt + 8) >> 3;
  const int n_it = qt + 1;
  const int bi = n_it / nseg, rem = n_it - bi * nseg;
  const int it0 = seg * bi + (seg < rem ? seg : rem);
  const int it1 = it0 + bi + (seg < rem ? 1 : 0);

  const int q0 = qt * 64;
  const int tid  = threadIdx.x;
  const int lane = tid & 63;
  const int wv   = tid >> 6;
  const int n    = lane & 15;
  const int quad = lane >> 4;

  __shared__ short Ks[64][136];
  __shared__ short Vs[128][72];
  __shared__ short Ps[4][16][72];   // [wave][q-local 16][KV 64 (+pad)]

  // Q fragments (B-operand for St; same mapping as A): q = q0 + wv*16 + n
  bf16x8 aQ[4];
  {
    const short* qrow = Qb + (size_t)(b * T_DIM + q0 + wv * 16 + n) * H_DIM;
#pragma unroll
    for (int kc = 0; kc < 4; kc++)
      aQ[kc] = *(const bf16x8*)(qrow + kc * 32 + quad * 8);
  }

  f32x4 accO[8];
#pragma unroll
  for (int i = 0; i < 8; i++) {
    f32x4 z = {0.f, 0.f, 0.f, 0.f};
    accO[i] = z;
  }
  float mrow = -1e30f;   // per-lane: running max for q-col (q0+wv*16+n)
  float lrow = 0.f;
  const float scale = 0.08838834764831845f;  // 1/sqrt(128)
  const int qg = q0 + wv * 16 + n;           // this lane's q (S^T col)

  const short* kbase = Kb + (size_t)b * T_DIM * H_DIM;
  const short* vbase = Vt + (size_t)b * H_DIM * T_DIM;
  const int krow = tid >> 4, kcol = (tid & 15) * 8;
  const int vrow = tid >> 3, vcol = (tid & 7) * 8;

  int4 kreg[4], vreg[4];
#pragma unroll
  for (int p = 0; p < 4; p++) {
    kreg[p] = *(const int4*)(kbase + (size_t)(it0 * 64 + krow + p * 16) * H_DIM + kcol);
    vreg[p] = *(const int4*)(vbase + (size_t)(vrow + p * 32) * T_DIM + it0 * 64 + vcol);
  }

  for (int it = it0; it < it1; ++it) {
    const int j0 = it * 64;
    __syncthreads();   // prev iter's Ks/Vs reads done
#pragma unroll
    for (int p = 0; p < 4; p++) *(int4*)&Ks[krow + p * 16][kcol] = kreg[p];
#pragma unroll
    for (int p = 0; p < 4; p++) *(int4*)&Vs[vrow + p * 32][vcol] = vreg[p];
    __syncthreads();   // staging visible
    if (it + 1 < it1) {   // prefetch next tile
#pragma unroll
      for (int p = 0; p < 4; p++) {
        kreg[p] = *(const int4*)(kbase + (size_t)(j0 + 64 + krow + p * 16) * H_DIM + kcol);
        vreg[p] = *(const int4*)(vbase + (size_t)(vrow + p * 32) * T_DIM + j0 + 64 + vcol);
      }
    }

    // St = K·Q^T  (K as A-operand, Q as B-operand; same frag mappings)
    // C layout: col = lane&15 = q-local, row = mt*16 + quad*4 + reg = KV-local
    f32x4 accS[4];
#pragma unroll
    for (int mt = 0; mt < 4; mt++) {
      f32x4 z = {0.f, 0.f, 0.f, 0.f};
      accS[mt] = z;
    }
#pragma unroll
    for (int mt = 0; mt < 4; mt++)
#pragma unroll
      for (int kc = 0; kc < 4; kc++) {
        bf16x8 aK = *(const bf16x8*)&Ks[mt * 16 + n][kc * 32 + quad * 8];
        accS[mt] = __builtin_amdgcn_mfma_f32_16x16x32_bf16(aK, aQ[kc], accS[mt], 0, 0, 0);
      }

    // scale + causal mask; column (= this lane's q) softmax is in-lane
    float sv[4][4];
    float mx = -1e30f;
#pragma unroll
    for (int mt = 0; mt < 4; mt++) {
      int kvb = j0 + mt * 16 + quad * 4;
#pragma unroll
      for (int i = 0; i < 4; i++) {
        float s = accS[mt][i] * scale;
        if (kvb + i > qg) s = -1e30f;
        sv[mt][i] = s;
        mx = fmaxf(mx, s);
      }
    }
    // cross-quad butterfly (lanes n, n+16, n+32, n+48)
    mx = fmaxf(mx, __shfl_xor(mx, 16, 64));
    mx = fmaxf(mx, __shfl_xor(mx, 32, 64));
    float mnew = fmaxf(mrow, mx);
    float alpha = __expf(mrow - mnew);
    mrow = mnew;
    float rsum = 0.f;
#pragma unroll
    for (int mt = 0; mt < 4; mt++)
#pragma unroll
      for (int i = 0; i < 4; i++) {
        float p = __expf(sv[mt][i] - mnew);
        rsum += p;
        Ps[wv][n][mt * 16 + quad * 4 + i] = f2bf(p);   // P^T -> P A-layout
      }
    rsum += __shfl_xor(rsum, 16, 64);
    rsum += __shfl_xor(rsum, 32, 64);
    lrow = lrow * alpha + rsum;

    // rescale accO: rows are q-local quad*4+i -> fetch alpha from lane holding
    // that q (bpermute, 4x)
    float aR[4];
#pragma unroll
    for (int i = 0; i < 4; i++) aR[i] = __shfl(alpha, quad * 4 + i, 64);
#pragma unroll
    for (int ht = 0; ht < 8; ht++)
#pragma unroll
      for (int i = 0; i < 4; i++)
        accO[ht][i] *= aR[i];

    // O += P·V  (Ps per-wave: in-wave DS ordering, no barrier needed)
    bf16x8 aP[2];
#pragma unroll
    for (int kc = 0; kc < 2; kc++)
      aP[kc] = *(const bf16x8*)&Ps[wv][n][kc * 32 + quad * 8];
#pragma unroll
    for (int ht = 0; ht < 8; ht++)
#pragma unroll
      for (int kc = 0; kc < 2; kc++) {
        bf16x8 bV = *(const bf16x8*)&Vs[ht * 16 + n][kc * 32 + quad * 8];
        accO[ht] = __builtin_amdgcn_mfma_f32_16x16x32_bf16(aP[kc], bV, accO[ht], 0, 0, 0);
      }
  }

  // partials out (unnormalized O; m, l per q-row)
  const int pid = b * 80 + f;
  float* Ob = Opart + (size_t)pid * 8192;
#pragma unroll
  for (int ht = 0; ht < 8; ht++)
#pragma unroll
    for (int i = 0; i < 4; i++)
      Ob[(wv * 16 + quad * 4 + i) * 128 + ht * 16 + n] = accO[ht][i];
  if (quad == 0) {   // lanes 0-15 hold m,l for q-local wv*16+n
    Ml[pid * 128 + wv * 16 + n] = mrow;
    Ml[pid * 128 + 64 + wv * 16 + n] = lrow;
  }
}

// ---------------------------------------------------------------------------
// attn pass 2: merge <=4 partials per (b, qt), normalize, write out fp32.
// ---------------------------------------------------------------------------
__global__ __launch_bounds__(256) void attn_merge(
    const float* __restrict__ Opart, const float* __restrict__ Ml,
    float* __restrict__ out) {
  const int qt = blockIdx.x, b = blockIdx.y;
  const int nseg = (qt + 8) >> 3;
  const int tid = threadIdx.x;
  const int row = tid >> 2, cg = tid & 3;
  const int pid0 = b * 80 + seg_prefix(qt);

  float m[4], l[4], w[4];
  float M = -1e30f;
  for (int s = 0; s < nseg; s++) {
    m[s] = Ml[(pid0 + s) * 128 + row];
    l[s] = Ml[(pid0 + s) * 128 + 64 + row];
    M = fmaxf(M, m[s]);
  }
  float L = 0.f;
  for (int s = 0; s < nseg; s++) {
    w[s] = __expf(m[s] - M);
    L += l[s] * w[s];
  }
  const float inv = 1.0f / L;

  const float* src0 = Opart + (size_t)pid0 * 8192 + row * 128 + cg * 32;
  float* dst = out + (size_t)(b * T_DIM + qt * 64 + row) * H_DIM + cg * 32;
#pragma unroll
  for (int j = 0; j < 8; j++) {
    float4 a = ((const float4*)(src0))[j];
    float4 r;
    r.x = a.x * w[0]; r.y = a.y * w[0]; r.z = a.z * w[0]; r.w = a.w * w[0];
    for (int s = 1; s < nseg; s++) {
      float4 c = ((const float4*)(src0 + s * 8192))[j];
      r.x += c.x * w[s]; r.y += c.y * w[s]; r.z += c.z * w[s]; r.w += c.w * w[s];
    }
    r.x *= inv; r.y *= inv; r.z *= inv; r.w *= inv;
    ((float4*)dst)[j] = r;
  }
}

// ---------------------------------------------------------------------------
extern "C" void kernel_launch(void* const* d_in, const int* in_sizes, int n_in,
                              void* d_out, int out_size, void* d_ws, size_t ws_size,
                              hipStream_t stream) {
  (void)in_sizes; (void)n_in; (void)out_size; (void)ws_size;
  const float* x  = (const float*)d_in[0];
  const float* Wk = (const float*)d_in[1];
  const float* Wq = (const float*)d_in[2];
  const float* Wv = (const float*)d_in[3];
  float* out = (float*)d_out;

  char* ws = (char*)d_ws;
  short* Wt = (short*)ws;                         //   786,432 B
  short* Qb = (short*)(ws + 786432);              // 4,194,304 B
  short* Kb = (short*)(ws + 786432 + 4194304);    // 4,194,304 B
  short* Vt = (short*)(ws + 786432 + 8388608);    // 4,194,304 B
  float* Opart = (float*)(ws + 13369344);         // 20,971,520 B
  float* Ml    = (float*)(ws + 34340864);         //    327,680 B  (peak 33.1 MiB)

  prep_kernel<<<dim3(1536), dim3(256), 0, stream>>>(Wk, Wq, Wv, Wt);
  proj_kernel<<<dim3(128, 3), dim3(256), 0, stream>>>(x, Wt, Kb, Qb, Vt);
  attn_part<<<dim3(80, 8), dim3(256), 0, stream>>>(Qb, Kb, Vt, Opart, Ml);
  attn_merge<<<dim3(32, 8), dim3(256), 0, stream>>>(Opart, Ml, out);
}